// Round 4
// baseline (485.753 us; speedup 1.0000x reference)
//
#include <hip/hip_runtime.h>

// Demosaic BG-Bayer (top-left red) -> RGB, closed-form stencil.
// Each thread computes a 2(row)x4(col) output block from 4 input rows:
//   a = row max(y-1,1), b = row y, c = row y+1, d = row min(y+2,2046)  (y even)
// Edge values (p[x0-1], p[x0+4]) come from neighboring lanes via shuffle:
// a wave's 64 lanes cover 64 consecutive 4-col strips of the same row
// (512 strips/row, waves never straddle rows since 512 % 64 == 0).
// Only lane 0 / lane 63 need a real load; the clamped cases (x0==0 -> p[1],
// x0==2044 -> p[2046]) resolve to the lane's own register (c.y / c.z).
//
// XCD swizzle: 16384 blocks, 8 XCDs -> each XCD gets 2048 consecutive
// logical blocks = exactly one batch image. Vertically adjacent row-pairs
// (which share 2 input rows) then hit the same per-XCD L2 instead of
// re-fetching from HBM.

#define HH 2048
#define WW 2048

__global__ __launch_bounds__(256) void demosaic_bg_kernel(const float* __restrict__ in,
                                                          float* __restrict__ out) {
    const int strips_per_row = WW / 4;  // 512

    // bijective XCD-aware remap (gridDim.x == 16384, divisible by 8)
    int bid = (int)blockIdx.x;
    int nb = (bid & 7) * ((int)gridDim.x >> 3) + (bid >> 3);
    int gid = nb * 256 + (int)threadIdx.x;

    int s = gid & (strips_per_row - 1);
    int t = gid >> 9;
    int yp = t & (HH / 2 - 1);   // row-pair index
    int bimg = t >> 10;          // batch
    int y = yp << 1;             // even
    int x0 = s << 2;
    int lane = (int)threadIdx.x & 63;

    const float* __restrict__ img = in + (size_t)bimg * HH * WW;

    const int i0 = (y == 0) ? 1 : y - 1;
    const int i3 = (y + 2 > HH - 2) ? (HH - 2) : y + 2;

    const float* pa = img + (size_t)i0 * WW;
    const float* pb = img + (size_t)y * WW;
    const float* pc = img + (size_t)(y + 1) * WW;
    const float* pd = img + (size_t)i3 * WW;

    float4 a = *(const float4*)(pa + x0);
    float4 b = *(const float4*)(pb + x0);
    float4 c = *(const float4*)(pc + x0);
    float4 d = *(const float4*)(pd + x0);

    // in-wave edge exchange (only la, lb, lc and rb, rc, rd are consumed)
    float la = __shfl_up(a.w, 1);
    float lb = __shfl_up(b.w, 1);
    float lc = __shfl_up(c.w, 1);
    float rb = __shfl_down(b.x, 1);
    float rc = __shfl_down(c.x, 1);
    float rd = __shfl_down(d.x, 1);

    if (lane == 0) {
        if (x0 == 0) {           // clamp: p[-1] -> p[1]
            la = a.y; lb = b.y; lc = c.y;
        } else {                 // strip boundary between waves: real load
            la = pa[x0 - 1]; lb = pb[x0 - 1]; lc = pc[x0 - 1];
        }
    }
    if (lane == 63) {
        if (x0 + 4 > WW - 2) {   // clamp: p[2048] -> p[2046] (x0 == 2044)
            rb = b.z; rc = c.z; rd = d.z;
        } else {
            rb = pb[x0 + 4]; rc = pc[x0 + 4]; rd = pd[x0 + 4];
        }
    }

    // ---- even output row y: [red, green, red, green] ----
    float4 Re, Ge, Be;
    Re.x = b.x;
    Ge.x = 0.25f * (a.x + c.x + lb + b.y);
    Be.x = 0.25f * (la + a.y + lc + c.y);

    Re.y = 0.5f * (b.x + b.z);
    Ge.y = b.y;
    Be.y = 0.5f * (a.y + c.y);

    Re.z = b.z;
    Ge.z = 0.25f * (a.z + c.z + b.y + b.w);
    Be.z = 0.25f * (a.y + a.w + c.y + c.w);

    Re.w = 0.5f * (b.z + rb);
    Ge.w = b.w;
    Be.w = 0.5f * (a.w + c.w);

    // ---- odd output row y+1: [green, blue, green, blue] ----
    float4 Ro, Go, Bo;
    Ro.x = 0.5f * (b.x + d.x);
    Go.x = c.x;
    Bo.x = 0.5f * (lc + c.y);

    Ro.y = 0.25f * (b.x + b.z + d.x + d.z);
    Go.y = 0.25f * (b.y + d.y + c.x + c.z);
    Bo.y = c.y;

    Ro.z = 0.5f * (b.z + d.z);
    Go.z = c.z;
    Bo.z = 0.5f * (c.y + c.w);

    Ro.w = 0.25f * (b.z + rb + d.z + rd);
    Go.w = 0.25f * (b.w + d.w + c.z + rc);
    Bo.w = c.w;

    const size_t plane = (size_t)HH * WW;
    size_t obase = (size_t)bimg * 3 * plane + (size_t)y * WW + x0;
    *(float4*)(out + obase)                  = Re;
    *(float4*)(out + obase + WW)             = Ro;
    *(float4*)(out + obase + plane)          = Ge;
    *(float4*)(out + obase + plane + WW)     = Go;
    *(float4*)(out + obase + 2 * plane)      = Be;
    *(float4*)(out + obase + 2 * plane + WW) = Bo;
}

extern "C" void kernel_launch(void* const* d_in, const int* in_sizes, int n_in,
                              void* d_out, int out_size, void* d_ws, size_t ws_size,
                              hipStream_t stream) {
    const float* in = (const float*)d_in[0];
    float* out = (float*)d_out;
    const int threads = 8 * (HH / 2) * (WW / 4);   // 4.19M
    dim3 block(256);
    dim3 grid(threads / 256);                      // 16384
    demosaic_bg_kernel<<<grid, block, 0, stream>>>(in, out);
}